// Round 12
// baseline (60.497 us; speedup 1.0000x reference)
//
#include <hip/hip_runtime.h>

typedef __bf16 bf16x8 __attribute__((ext_vector_type(8)));
typedef float f32x4 __attribute__((ext_vector_type(4)));
typedef unsigned short u16x8 __attribute__((ext_vector_type(8)));
typedef unsigned short u16x4 __attribute__((ext_vector_type(4)));

#define B_ 32
#define CC 512
#define HW 192
#define C8_ 64
#define NTRI 528
#define NG3 2112          // 4 quarter-tiles (96x96) per pair
#define QBUF_B 12288      // one buffer: A(96x32) + B(96x32) bf16, 64B rows

__device__ inline unsigned short f2bf(float f) {
    unsigned u = __float_as_uint(f);
    unsigned r = (u + 0x7FFFu + ((u >> 16) & 1u)) >> 16;
    return (unsigned short)r;
}

__device__ inline void gload16(const void* g, void* l) {
    __builtin_amdgcn_global_load_lds(
        (const __attribute__((address_space(1))) unsigned*)g,
        (__attribute__((address_space(3))) unsigned*)l,
        16, 0, 0);
}

// ---------------- Kernel 1 (fused prep): transpose + weight precast ---------
__global__ void prep(const float* __restrict__ x,
                     const float* __restrict__ Wq, const float* __restrict__ Wk,
                     unsigned short* __restrict__ xt,
                     unsigned short* __restrict__ wqb, unsigned short* __restrict__ wkb) {
    __shared__ unsigned short tile[64 * 64];
    int t = threadIdx.x;
    if (blockIdx.x >= 96) {
        int id = (blockIdx.x - 96) * 8 + blockIdx.y;     // 0..63
        const float* src = (id < 32) ? Wq : Wk;
        unsigned short* dst = (id < 32) ? wqb : wkb;
        int base = (id & 31) * 1024 + t * 4;
        f32x4 a = *(const f32x4*)(src + base);
        u16x4 o;
        #pragma unroll
        for (int e = 0; e < 4; ++e) o[e] = f2bf(a[e]);
        *(u16x4*)(dst + base) = o;
        return;
    }
    int b = blockIdx.x / 3, mt = blockIdx.x % 3;
    int m0 = mt * 64, c0 = blockIdx.y * 64;
    const float* xb = x + (size_t)b * CC * HW + (size_t)c0 * HW + m0;

    int mq = t & 15, cl0 = t >> 4;
    int sw = (mq & 7) << 3;
    #pragma unroll
    for (int rd = 0; rd < 4; ++rd) {
        int cl = rd * 16 + cl0;
        f32x4 v = *(const f32x4*)(xb + cl * HW + mq * 4);
        #pragma unroll
        for (int e = 0; e < 4; ++e)
            tile[(mq * 4 + e) * 64 + (cl ^ sw)] = f2bf(v[e]);
    }
    __syncthreads();
    unsigned short* xo = xt + ((size_t)b * HW + m0) * CC + c0;
    int kc = t & 7, mr0 = t >> 3;
    #pragma unroll
    for (int rd = 0; rd < 2; ++rd) {
        int mr = rd * 32 + mr0;
        u16x8 v = *(const u16x8*)&tile[mr * 64 + ((kc << 3) ^ (((mr >> 2) & 7) << 3))];
        *(u16x8*)(xo + (size_t)mr * CC + kc * 8) = v;
    }
}

// ---------------- Kernel 2: q/k projections via MFMA (round-7 verbatim) -----
__global__ __launch_bounds__(256) void pam_qk(
        const unsigned short* __restrict__ xt,
        const unsigned short* __restrict__ wqb, const unsigned short* __restrict__ wkb,
        const float* __restrict__ bq, const float* __restrict__ bk,
        unsigned short* __restrict__ qo, unsigned short* __restrict__ ko) {
    int b = blockIdx.x, m0 = blockIdx.y * 48;
    int tid = threadIdx.x, w = tid >> 6, lane = tid & 63;
    int l15 = lane & 15, lq = lane >> 4;
    int qc = w * 16 + l15;

    f32x4 accq[3], acck[3];
    #pragma unroll
    for (int i = 0; i < 3; ++i) {
        accq[i] = (f32x4){0.f, 0.f, 0.f, 0.f};
        acck[i] = (f32x4){0.f, 0.f, 0.f, 0.f};
    }

    const unsigned short* xb = xt + ((size_t)b * HW + m0) * CC;
    const unsigned short* wqp = wqb + (size_t)qc * CC;
    const unsigned short* wkp = wkb + (size_t)qc * CC;

    for (int kt = 0; kt < 16; ++kt) {
        int ko8 = kt * 32 + lq * 8;
        bf16x8 wqf = *(const bf16x8*)(wqp + ko8);
        bf16x8 wkf = *(const bf16x8*)(wkp + ko8);
        bf16x8 af[3];
        #pragma unroll
        for (int i = 0; i < 3; ++i)
            af[i] = *(const bf16x8*)(xb + (i * 16 + l15) * CC + ko8);
        #pragma unroll
        for (int i = 0; i < 3; ++i) {
            accq[i] = __builtin_amdgcn_mfma_f32_16x16x32_bf16(af[i], wqf, accq[i], 0, 0, 0);
            acck[i] = __builtin_amdgcn_mfma_f32_16x16x32_bf16(af[i], wkf, acck[i], 0, 0, 0);
        }
    }

    float bqv = bq[qc], bkv = bk[qc];
    #pragma unroll
    for (int i = 0; i < 3; ++i) {
        #pragma unroll
        for (int r = 0; r < 4; ++r) {
            int m = m0 + i * 16 + lq * 4 + r;
            qo[((size_t)b * HW + m) * C8_ + qc] = f2bf(accq[i][r] + bqv);
            ko[((size_t)b * HW + m) * C8_ + qc] = f2bf(acck[i][r] + bkv);
        }
    }
}

// ---------------- Kernel 3: Gram quarter-tiles (96x96), ~5 blocks/CU --------
// 2112 blocks x 256 thr (4 waves, 2x2 of 48x48). BK=32, dbuf, drain barriers.
// Partial rowmax/colmax (96 each) -> ws2[pair][i][j][0:96 row | 96:192 col].
__global__ __launch_bounds__(256, 5) void gram3(const unsigned short* __restrict__ xt,
                                                float* __restrict__ ws2) {
    __shared__ __attribute__((aligned(16))) char smem[2 * QBUF_B];

    int tid = threadIdx.x;
    int bid = (blockIdx.x & 7) * 264 + (blockIdx.x >> 3);   // 2112 = 8*264
    int pairid = bid >> 2, qi = (bid >> 1) & 1, qj = bid & 1;
    int idx = pairid, g = 0;
    while (idx >= B_ - g) { idx -= B_ - g; ++g; }
    int p = g + idx;

    const unsigned short* xga = xt + ((size_t)g * HW + 96 * qi) * CC;  // A: 96 rows
    const unsigned short* xpb = xt + ((size_t)p * HW + 96 * qj) * CC;  // B: 96 rows

    int w = tid >> 6, lane = tid & 63;
    int wr = w >> 1, wc = w & 1;                // 2 x 2 wave grid
    int l15 = lane & 15, lq = lane >> 4;

    // staging: 3 chunks/thread; q = tid + 256*ci. q<384: A (row q>>2, slot q&3),
    // else B. Global src pre-applies inverse swizzle: logical chunk s^((r>>1)&3).
    const unsigned short* sp[3];
    unsigned lo[3];
    #pragma unroll
    for (int ci = 0; ci < 3; ++ci) {
        int q = tid + 256 * ci;
        lo[ci] = (unsigned)q * 16;
        int q2 = (q < 384) ? q : q - 384;
        int r = q2 >> 2, s = q2 & 3;
        sp[ci] = ((q < 384) ? xga : xpb) + r * CC + (((s ^ ((r >> 1) & 3)) << 3));
    }

    // read offsets (byte): row*64 + ((lq ^ ((row>>1)&3))<<4); B tile at +6144
    unsigned aoff[3], boff[3];
    #pragma unroll
    for (int i = 0; i < 3; ++i) {
        int row = wr * 48 + i * 16 + l15;
        aoff[i] = (unsigned)row * 64 + ((unsigned)(lq ^ ((row >> 1) & 3)) << 4);
    }
    #pragma unroll
    for (int j = 0; j < 3; ++j) {
        int n = wc * 48 + j * 16 + l15;
        boff[j] = 6144u + (unsigned)n * 64 + ((unsigned)(lq ^ ((n >> 1) & 3)) << 4);
    }

    f32x4 acc[3][3];
    #pragma unroll
    for (int i = 0; i < 3; ++i)
        #pragma unroll
        for (int j = 0; j < 3; ++j)
            acc[i][j] = (f32x4){0.f, 0.f, 0.f, 0.f};

    #define STG3(buf, kt)                                                      \
        {                                                                      \
            char* base = smem + (buf) * QBUF_B;                                \
            int k0 = (kt) * 32;                                                \
            gload16(sp[0] + k0, base + lo[0]);                                 \
            gload16(sp[1] + k0, base + lo[1]);                                 \
            gload16(sp[2] + k0, base + lo[2]);                                 \
        }

    #define CMP3(buf)                                                          \
        {                                                                      \
            const char* Bb = smem + (buf) * QBUF_B;                            \
            bf16x8 af[3], bfr[3];                                              \
            _Pragma("unroll")                                                  \
            for (int i = 0; i < 3; ++i)                                        \
                af[i] = *(const bf16x8*)(Bb + aoff[i]);                        \
            _Pragma("unroll")                                                  \
            for (int j = 0; j < 3; ++j)                                        \
                bfr[j] = *(const bf16x8*)(Bb + boff[j]);                       \
            _Pragma("unroll")                                                  \
            for (int i = 0; i < 3; ++i)                                        \
                _Pragma("unroll")                                              \
                for (int j = 0; j < 3; ++j)                                    \
                    acc[i][j] = __builtin_amdgcn_mfma_f32_16x16x32_bf16(       \
                        af[i], bfr[j], acc[i][j], 0, 0, 0);                    \
        }

    STG3(0, 0);
    __syncthreads();
    for (int kt = 0; kt < 16; ++kt) {
        int cur = kt & 1;
        if (kt < 15) STG3(cur ^ 1, kt + 1);
        CMP3(cur);
        __syncthreads();
    }

    // ---- epilogue: partial reductions (smem reusable after final sync)
    float* rowred = (float*)smem;            // [2][96]
    float* colred = (float*)(smem + 768);    // [2][96]

    #pragma unroll
    for (int i = 0; i < 3; ++i) {            // rowmax over this block's 96 n
        float rm[4];
        #pragma unroll
        for (int r = 0; r < 4; ++r) rm[r] = -1e30f;
        #pragma unroll
        for (int j = 0; j < 3; ++j)
            #pragma unroll
            for (int r = 0; r < 4; ++r)
                rm[r] = fmaxf(rm[r], acc[i][j][r]);
        #pragma unroll
        for (int msk = 1; msk <= 8; msk <<= 1)
            #pragma unroll
            for (int r = 0; r < 4; ++r)
                rm[r] = fmaxf(rm[r], __shfl_xor(rm[r], msk));
        if (l15 == 0) {
            #pragma unroll
            for (int r = 0; r < 4; ++r)
                rowred[wc * 96 + wr * 48 + i * 16 + lq * 4 + r] = rm[r];
        }
    }
    #pragma unroll
    for (int j = 0; j < 3; ++j) {            // colmax over this block's 96 m
        float cm = -1e30f;
        #pragma unroll
        for (int i = 0; i < 3; ++i)
            #pragma unroll
            for (int r = 0; r < 4; ++r)
                cm = fmaxf(cm, acc[i][j][r]);
        cm = fmaxf(cm, __shfl_xor(cm, 16));
        cm = fmaxf(cm, __shfl_xor(cm, 32));
        if (lane < 16) colred[wr * 96 + wc * 48 + j * 16 + l15] = cm;
    }
    __syncthreads();
    float* dst = ws2 + (size_t)(pairid * 4 + qi * 2 + qj) * 192;
    if (tid < 96)
        dst[tid] = fmaxf(rowred[tid], rowred[96 + tid]);
    else if (tid < 192) {
        int n = tid - 96;
        dst[96 + n] = fmaxf(colred[n], colred[96 + n]);
    }
}

// ---------------- Kernel 4 (fused): pam_energy (0..127) + finalize (128..655)
__global__ __launch_bounds__(256) void energy_fin(
        const unsigned short* __restrict__ qo,
        const unsigned short* __restrict__ ko,
        const float* __restrict__ ws2,
        float* __restrict__ out) {
    int tid = threadIdx.x;
    if (blockIdx.x >= 128) {
        int pairid = blockIdx.x - 128;
        int idx = pairid, g = 0;
        while (idx >= B_ - g) { idx -= B_ - g; ++g; }
        int p = g + idx;
        const float* wp = ws2 + (size_t)pairid * 768;  // [i][j][192]
        #pragma unroll
        for (int half = 0; half < 2; ++half) {
            int k = half * 256 + tid;                  // 0..383 over two halves
            if (k < 192) {                             // colmax -> out[g][p][n]
                int j = k / 96, nn = k % 96;
                out[((size_t)g * B_ + p) * HW + k] =
                    fmaxf(wp[(0 * 2 + j) * 192 + 96 + nn],
                          wp[(1 * 2 + j) * 192 + 96 + nn]);
            } else if (k < 384) {                      // rowmax -> out[p][g][m]
                int m = k - 192, i = m / 96, mm = m % 96;
                out[((size_t)p * B_ + g) * HW + m] =
                    fmaxf(wp[(i * 2 + 0) * 192 + mm],
                          wp[(i * 2 + 1) * 192 + mm]);
            }
        }
        return;
    }
    int b = blockIdx.x >> 2, m0 = (blockIdx.x & 3) * 48;
    int w = tid >> 6, lane = tid & 63;
    int l15 = lane & 15, lq = lane >> 4;
    int n0 = w * 48;

    f32x4 acc[3][3];
    #pragma unroll
    for (int i = 0; i < 3; ++i)
        #pragma unroll
        for (int j = 0; j < 3; ++j)
            acc[i][j] = (f32x4){0.f, 0.f, 0.f, 0.f};

    const unsigned short* qb = qo + ((size_t)b * HW + m0) * C8_;
    const unsigned short* kb = ko + ((size_t)b * HW + n0) * C8_;

    #pragma unroll
    for (int kt = 0; kt < 2; ++kt) {
        int ko8 = kt * 32 + lq * 8;
        bf16x8 af[3], bfr[3];
        #pragma unroll
        for (int i = 0; i < 3; ++i)
            af[i] = *(const bf16x8*)(qb + (i * 16 + l15) * C8_ + ko8);
        #pragma unroll
        for (int j = 0; j < 3; ++j)
            bfr[j] = *(const bf16x8*)(kb + (j * 16 + l15) * C8_ + ko8);
        #pragma unroll
        for (int i = 0; i < 3; ++i)
            #pragma unroll
            for (int j = 0; j < 3; ++j)
                acc[i][j] = __builtin_amdgcn_mfma_f32_16x16x32_bf16(af[i], bfr[j], acc[i][j], 0, 0, 0);
    }

    __shared__ float red[4][48];
    #pragma unroll
    for (int i = 0; i < 3; ++i) {
        float rm[4];
        #pragma unroll
        for (int r = 0; r < 4; ++r) rm[r] = -1e30f;
        #pragma unroll
        for (int j = 0; j < 3; ++j)
            #pragma unroll
            for (int r = 0; r < 4; ++r)
                rm[r] = fmaxf(rm[r], acc[i][j][r]);
        #pragma unroll
        for (int msk = 1; msk <= 8; msk <<= 1)
            #pragma unroll
            for (int r = 0; r < 4; ++r)
                rm[r] = fmaxf(rm[r], __shfl_xor(rm[r], msk));
        if (l15 == 0) {
            #pragma unroll
            for (int r = 0; r < 4; ++r)
                red[w][i * 16 + lq * 4 + r] = rm[r];
        }
    }
    __syncthreads();
    if (tid < 48) {
        float v = fmaxf(fmaxf(red[0][tid], red[1][tid]),
                        fmaxf(red[2][tid], red[3][tid]));
        out[((size_t)B_ * B_ + b) * HW + m0 + tid] = v;
    }
}

extern "C" void kernel_launch(void* const* d_in, const int* in_sizes, int n_in,
                              void* d_out, int out_size, void* d_ws, size_t ws_size,
                              hipStream_t stream) {
    (void)in_sizes; (void)n_in; (void)out_size; (void)ws_size;
    const float* x  = (const float*)d_in[0];
    const float* Wq = (const float*)d_in[1];
    const float* bq = (const float*)d_in[2];
    const float* Wk = (const float*)d_in[3];
    const float* bk = (const float*)d_in[4];
    float* out = (float*)d_out;

    char* ws = (char*)d_ws;
    unsigned short* xt  = (unsigned short*)ws;                        // 6291456 B
    unsigned short* wqb = (unsigned short*)(ws + 6291456);            // 65536 B
    unsigned short* wkb = (unsigned short*)(ws + 6291456 + 65536);    // 65536 B
    unsigned short* qbuf = (unsigned short*)(ws + 6291456 + 131072);  // 786432 B
    unsigned short* kbuf = (unsigned short*)(ws + 6291456 + 131072 + 786432);
    float* ws2 = (float*)(ws + 6291456 + 131072 + 2 * 786432);        // 1622016 B

    prep<<<dim3(104, 8), dim3(256), 0, stream>>>(x, Wq, Wk, xt, wqb, wkb);
    pam_qk<<<dim3(32, 4), dim3(256), 0, stream>>>(xt, wqb, wkb, bq, bk, qbuf, kbuf);
    gram3<<<dim3(NG3), dim3(256), 0, stream>>>(xt, ws2);
    energy_fin<<<dim3(656), dim3(256), 0, stream>>>(qbuf, kbuf, ws2, out);
}